// Round 6
// baseline (222.671 us; speedup 1.0000x reference)
//
#include <hip/hip_runtime.h>

#define B_ 16
#define D_ 64
#define T_ 4096
#define K_ 512
#define N_ (B_*T_)        // 65536 vectors
#define Q_ (B_*D_*T_)     // 4194304 quantized elements
#define ENC_OFF ((size_t)(2 + Q_))  // encodings start in d_out

// ws layout (bytes) — ~136 KB
#define WS_LOSS    0        // double
#define WS_DONE    8        // int (blocks-finished counter)
#define WS_HIST    16       // int[512]
#define WS_NE      2064     // float[512]
#define WS_CBH     4608     // bf16x8[32*2*64]  (64 KB) codebook hi frags
#define WS_CBL     70144    // bf16x8[32*2*64]  (64 KB) codebook lo frags

typedef __bf16 bf16x8 __attribute__((ext_vector_type(8)));
typedef float  f32x4  __attribute__((ext_vector_type(4)));

// ---------------- K0: init + ne + codebook hi/lo B-fragments ----------------
// Grid = 8 blocks x 256 threads.
__global__ __launch_bounds__(256) void k0_init(const float* __restrict__ cb,
                                               float* __restrict__ ne,
                                               int* __restrict__ hist,
                                               double* __restrict__ loss,
                                               int* __restrict__ done,
                                               bf16x8* __restrict__ cbh,
                                               bf16x8* __restrict__ cbl) {
    int bidx = blockIdx.x, tid = threadIdx.x;

    // ne for codes [bidx*64, bidx*64+64)
    if (tid < 64) {
        int code = bidx * 64 + tid;
        float s = 0.f;
#pragma unroll
        for (int d = 0; d < 64; ++d) { float c = cb[code*64 + d]; s = fmaf(c, c, s); }
        ne[code] = s;
    }
    if (bidx == 0) {
        hist[tid] = 0; hist[tid + 256] = 0;
        if (tid == 0) { *loss = 0.0; *done = 0; }
    }

    // B-frag element (ct,ks,lane,j) = cb[ct*16 + (lane&15)][ks*32 + (lane>>4)*8 + j]
    // This block handles ct in [bidx*4, bidx*4+4): 512 frag-pairs, 2 per thread.
#pragma unroll
    for (int p = 0; p < 2; ++p) {
        int e = p * 256 + tid;          // 0..511
        int ct = bidx * 4 + (e >> 7);
        int ks = (e >> 6) & 1;
        int lane = e & 63;
        int code  = ct * 16 + (lane & 15);
        int dbase = ks * 32 + ((lane >> 4) << 3);
        bf16x8 h, l;
#pragma unroll
        for (int j = 0; j < 8; ++j) {
            float v = cb[code * 64 + dbase + j];
            __bf16 hv = (__bf16)v;
            __bf16 lv = (__bf16)(v - (float)hv);
            h[j] = hv; l[j] = lv;
        }
        cbh[(ct * 2 + ks) * 64 + lane] = h;
        cbl[(ct * 2 + ks) * 64 + lane] = l;
    }
}

// ---------------- K_MAIN: stage + MFMA argmin + one-hot + quant + loss ------
// Block = 256 thr = 4 waves = 128 rows (8 row-tiles); grid = 512.
// Last block to finish also computes perplexity + final loss (k6 fused).
__global__ __launch_bounds__(256) void k_main(const float* __restrict__ in,
                                              const float* __restrict__ cb,
                                              const bf16x8* __restrict__ cbh,
                                              const bf16x8* __restrict__ cbl,
                                              const float* __restrict__ ne,
                                              float* __restrict__ out,
                                              float2* __restrict__ enc2,
                                              int* __restrict__ hist,
                                              double* __restrict__ loss,
                                              int* __restrict__ done) {
    __shared__ float X[64][129];     // 33 KB; all access patterns <=2-way alias (free)
    __shared__ float ne_s[512];
    __shared__ int   sidx[128];
    int tid = threadIdx.x;
    int n0 = blockIdx.x * 128;
    int b  = n0 >> 12, t0 = n0 & (T_ - 1);

    { // stage x-tile: 8192 floats, 32 per thread, coalesced
        int tl = tid & 127, dg = tid >> 7;
#pragma unroll
        for (int i = 0; i < 32; ++i) {
            int d = dg * 32 + i;
            X[d][tl] = in[((size_t)b * 64 + d) * T_ + t0 + tl];
        }
    }
    ne_s[tid] = ne[tid];
    ne_s[tid + 256] = ne[tid + 256];
    __syncthreads();

    int w = tid >> 6, lane = tid & 63;
    int col = lane & 15, q = lane >> 4;

    // A-frags: A[m][k=ks*32+q*8+j] = x_row[d], hi/lo bf16 split
    bf16x8 Ah[2][2], Al[2][2];
#pragma unroll
    for (int r = 0; r < 2; ++r) {
        int rl = (w * 2 + r) * 16 + col;      // local row
#pragma unroll
        for (int ks = 0; ks < 2; ++ks) {
            bf16x8 h, l;
#pragma unroll
            for (int j = 0; j < 8; ++j) {
                float v = X[ks * 32 + q * 8 + j][rl];
                __bf16 hv = (__bf16)v;
                __bf16 lv = (__bf16)(v - (float)hv);
                h[j] = hv; l[j] = lv;
            }
            Ah[r][ks] = h; Al[r][ks] = l;
        }
    }

    float m1[2][4]; int i1[2][4];
#pragma unroll
    for (int r = 0; r < 2; ++r)
#pragma unroll
        for (int e = 0; e < 4; ++e) { m1[r][e] = 3.4e38f; i1[r][e] = 0; }

    for (int ct = 0; ct < 32; ++ct) {
        bf16x8 Bh0 = cbh[(ct * 2 + 0) * 64 + lane];
        bf16x8 Bh1 = cbh[(ct * 2 + 1) * 64 + lane];
        bf16x8 Bl0 = cbl[(ct * 2 + 0) * 64 + lane];
        bf16x8 Bl1 = cbl[(ct * 2 + 1) * 64 + lane];
        float nev = ne_s[ct * 16 + col];
        int code = ct * 16 + col;
#pragma unroll
        for (int r = 0; r < 2; ++r) {
            f32x4 acc = {0.f, 0.f, 0.f, 0.f};
            acc = __builtin_amdgcn_mfma_f32_16x16x32_bf16(Ah[r][0], Bh0, acc, 0, 0, 0);
            acc = __builtin_amdgcn_mfma_f32_16x16x32_bf16(Ah[r][1], Bh1, acc, 0, 0, 0);
            acc = __builtin_amdgcn_mfma_f32_16x16x32_bf16(Ah[r][0], Bl0, acc, 0, 0, 0);
            acc = __builtin_amdgcn_mfma_f32_16x16x32_bf16(Al[r][0], Bh0, acc, 0, 0, 0);
            acc = __builtin_amdgcn_mfma_f32_16x16x32_bf16(Ah[r][1], Bl1, acc, 0, 0, 0);
            acc = __builtin_amdgcn_mfma_f32_16x16x32_bf16(Al[r][1], Bh1, acc, 0, 0, 0);
            // lo*lo terms ~2^-32 relative: negligible, dropped
#pragma unroll
            for (int e = 0; e < 4; ++e) {
                float sc = fmaf(-2.f, acc[e], nev);   // ||e||^2 - 2 x.e
                bool lt = sc < m1[r][e];
                i1[r][e] = lt ? code : i1[r][e];
                m1[r][e] = lt ? sc : m1[r][e];
            }
        }
    }

    // argmin across the 16 lanes (same q) holding this row's columns
#pragma unroll
    for (int r = 0; r < 2; ++r)
#pragma unroll
        for (int e = 0; e < 4; ++e) {
            float a1 = m1[r][e]; int ai = i1[r][e];
#pragma unroll
            for (int off = 1; off < 16; off <<= 1) {
                float o1 = __shfl_xor(a1, off);
                int   oi = __shfl_xor(ai, off);
                bool tk = (o1 < a1) || (o1 == a1 && oi < ai);  // tie -> lower index
                a1 = tk ? o1 : a1; ai = tk ? oi : ai;
            }
            if (col == 0) sidx[(w * 2 + r) * 16 + q * 4 + e] = ai;
        }
    __syncthreads();

    // --- one-hot rows: 256 float2 cols per row, 128 rows (base 8B-aligned) ---
#pragma unroll 4
    for (int i = 0; i < 128; ++i) {
        int id = sidx[i];                      // uniform LDS read -> broadcast
        float2 v;
        v.x = ((id >> 1) == tid && (id & 1) == 0) ? 1.f : 0.f;
        v.y = ((id >> 1) == tid && (id & 1) == 1) ? 1.f : 0.f;
        enc2[(size_t)(n0 + i) * 256 + tid] = v;
    }

    // --- quantized + loss: lane = row, 32 dims per thread ---
    int tl = tid & 127, dg = tid >> 7;
    int idq = sidx[tl];
    const float4* cq4 = (const float4*)(cb + (size_t)idq * 64 + dg * 32);
    float* qp = out + 1 + (size_t)b * D_ * T_ + (size_t)(dg * 32) * T_ + t0 + tl;

    float lsum = 0.f;
#pragma unroll
    for (int j4 = 0; j4 < 8; ++j4) {
        float4 qv = cq4[j4];
        float qe[4] = {qv.x, qv.y, qv.z, qv.w};
#pragma unroll
        for (int e = 0; e < 4; ++e) {
            int dl = j4 * 4 + e;               // 0..31
            float xv = X[dg * 32 + dl][tl];
            float diff = qe[e] - xv;
            lsum = fmaf(diff, diff, lsum);
            qp[(size_t)dl * T_] = xv + diff;   // straight-through: x + (q - x)
        }
    }
    if (tid < 128) atomicAdd(&hist[idq], 1);   // one count per row (device scope)

#pragma unroll
    for (int off = 32; off > 0; off >>= 1) lsum += __shfl_down(lsum, off);
    __shared__ float wsum[4];
    __shared__ int last_s;
    if ((tid & 63) == 0) wsum[tid >> 6] = lsum;
    __syncthreads();
    if (tid == 0) {
        double s = (double)wsum[0] + (double)wsum[1] + (double)wsum[2] + (double)wsum[3];
        atomicAdd(loss, s);
        __threadfence();                        // publish hist/loss before done++
        int old = atomicAdd(done, 1);
        last_s = (old == 511) ? 1 : 0;
    }
    __syncthreads();
    if (!last_s) return;

    // --- fused finalize (k6): only the last block reaches here ---
    // Read hist/loss via atomics so stale L1/L2 (cross-XCD) can't be served.
    __shared__ double sh[256];
    int h0 = atomicAdd(&hist[tid], 0);
    int h1 = atomicAdd(&hist[tid + 256], 0);
    double p0 = (double)h0 / (double)N_;
    double p1 = (double)h1 / (double)N_;
    sh[tid] = p0 * log(p0 + 1e-10) + p1 * log(p1 + 1e-10);
    __syncthreads();
    for (int s = 128; s > 0; s >>= 1) {
        if (tid < s) sh[tid] += sh[tid + s];
        __syncthreads();
    }
    if (tid == 0) {
        double ls = atomicAdd(loss, 0.0);       // device-scope read-back
        out[1 + Q_] = (float)exp(-sh[0]);       // perplexity
        out[0] = (float)(1.25 * ls / (double)Q_);  // q_loss + 0.25*e_loss
    }
}

extern "C" void kernel_launch(void* const* d_in, const int* in_sizes, int n_in,
                              void* d_out, int out_size, void* d_ws, size_t ws_size,
                              hipStream_t stream) {
    const float* in = (const float*)d_in[0];   // [16, 64, 4096] fp32
    const float* cb = (const float*)d_in[1];   // [512, 64] fp32
    float* out = (float*)d_out;
    char* ws = (char*)d_ws;

    double* loss  = (double*)(ws + WS_LOSS);
    int* done     = (int*)(ws + WS_DONE);
    int* hist     = (int*)(ws + WS_HIST);
    float* ne     = (float*)(ws + WS_NE);
    bf16x8* cbh   = (bf16x8*)(ws + WS_CBH);
    bf16x8* cbl   = (bf16x8*)(ws + WS_CBL);

    float2* enc2 = (float2*)(out + ENC_OFF);

    k0_init<<<8, 256, 0, stream>>>(cb, ne, hist, loss, done, cbh, cbl);
    k_main<<<512, 256, 0, stream>>>(in, cb, cbh, cbl, ne, out, enc2, hist, loss, done);
}

// Round 8
// 207.996 us; speedup vs baseline: 1.0706x; 1.0706x over previous
//
#include <hip/hip_runtime.h>

#define B_ 16
#define D_ 64
#define T_ 4096
#define K_ 512
#define N_ (B_*T_)        // 65536 vectors
#define Q_ (B_*D_*T_)     // 4194304 quantized elements
#define ENC_OFF ((size_t)(2 + Q_))  // encodings start in d_out

// ws layout (bytes) — ~136 KB
#define WS_LOSS    0        // double
#define WS_HIST    16       // int[512]
#define WS_NE      2064     // float[512]
#define WS_CBH     4608     // bf16x8[32*2*64]  (64 KB) codebook hi frags
#define WS_CBL     70144    // bf16x8[32*2*64]  (64 KB) codebook lo frags

typedef __bf16 bf16x8 __attribute__((ext_vector_type(8)));
typedef float  f32x4  __attribute__((ext_vector_type(4)));
typedef float  f32x2  __attribute__((ext_vector_type(2)));  // native vec for NT stores

// ---------------- K0: init + ne + codebook hi/lo B-fragments ----------------
// Grid = 8 blocks x 256 threads.
__global__ __launch_bounds__(256) void k0_init(const float* __restrict__ cb,
                                               float* __restrict__ ne,
                                               int* __restrict__ hist,
                                               double* __restrict__ loss,
                                               bf16x8* __restrict__ cbh,
                                               bf16x8* __restrict__ cbl) {
    int bidx = blockIdx.x, tid = threadIdx.x;

    // ne for codes [bidx*64, bidx*64+64)
    if (tid < 64) {
        int code = bidx * 64 + tid;
        float s = 0.f;
#pragma unroll
        for (int d = 0; d < 64; ++d) { float c = cb[code*64 + d]; s = fmaf(c, c, s); }
        ne[code] = s;
    }
    if (bidx == 0) {
        hist[tid] = 0; hist[tid + 256] = 0;
        if (tid == 0) *loss = 0.0;
    }

    // B-frag element (ct,ks,lane,j) = cb[ct*16 + (lane&15)][ks*32 + (lane>>4)*8 + j]
#pragma unroll
    for (int p = 0; p < 2; ++p) {
        int e = p * 256 + tid;          // 0..511
        int ct = bidx * 4 + (e >> 7);
        int ks = (e >> 6) & 1;
        int lane = e & 63;
        int code  = ct * 16 + (lane & 15);
        int dbase = ks * 32 + ((lane >> 4) << 3);
        bf16x8 h, l;
#pragma unroll
        for (int j = 0; j < 8; ++j) {
            float v = cb[code * 64 + dbase + j];
            __bf16 hv = (__bf16)v;
            __bf16 lv = (__bf16)(v - (float)hv);
            h[j] = hv; l[j] = lv;
        }
        cbh[(ct * 2 + ks) * 64 + lane] = h;
        cbl[(ct * 2 + ks) * 64 + lane] = l;
    }
}

// ---------------- K_MAIN: stage + MFMA argmin + one-hot + quant + loss ------
// Block = 256 thr = 4 waves = 128 rows (8 row-tiles); grid = 512.
// All big output stores are NONTEMPORAL: 153 MB streams to HBM without
// thrashing L2 (R6 counters: 1.7 TB/s with cached stores = eviction-bound).
__global__ __launch_bounds__(256) void k_main(const float* __restrict__ in,
                                              const float* __restrict__ cb,
                                              const bf16x8* __restrict__ cbh,
                                              const bf16x8* __restrict__ cbl,
                                              const float* __restrict__ ne,
                                              float* __restrict__ out,
                                              f32x2* __restrict__ enc2,
                                              int* __restrict__ hist,
                                              double* __restrict__ loss) {
    __shared__ float X[64][129];     // 33 KB; all access patterns <=2-way alias (free)
    __shared__ float ne_s[512];
    __shared__ int   sidx[128];
    int tid = threadIdx.x;
    int n0 = blockIdx.x * 128;
    int b  = n0 >> 12, t0 = n0 & (T_ - 1);

    { // stage x-tile: 8192 floats, 32 per thread, coalesced
        int tl = tid & 127, dg = tid >> 7;
#pragma unroll
        for (int i = 0; i < 32; ++i) {
            int d = dg * 32 + i;
            X[d][tl] = in[((size_t)b * 64 + d) * T_ + t0 + tl];
        }
    }
    ne_s[tid] = ne[tid];
    ne_s[tid + 256] = ne[tid + 256];
    __syncthreads();

    int w = tid >> 6, lane = tid & 63;
    int col = lane & 15, q = lane >> 4;

    // A-frags: A[m][k=ks*32+q*8+j] = x_row[d], hi/lo bf16 split
    bf16x8 Ah[2][2], Al[2][2];
#pragma unroll
    for (int r = 0; r < 2; ++r) {
        int rl = (w * 2 + r) * 16 + col;      // local row
#pragma unroll
        for (int ks = 0; ks < 2; ++ks) {
            bf16x8 h, l;
#pragma unroll
            for (int j = 0; j < 8; ++j) {
                float v = X[ks * 32 + q * 8 + j][rl];
                __bf16 hv = (__bf16)v;
                __bf16 lv = (__bf16)(v - (float)hv);
                h[j] = hv; l[j] = lv;
            }
            Ah[r][ks] = h; Al[r][ks] = l;
        }
    }

    float m1[2][4]; int i1[2][4];
#pragma unroll
    for (int r = 0; r < 2; ++r)
#pragma unroll
        for (int e = 0; e < 4; ++e) { m1[r][e] = 3.4e38f; i1[r][e] = 0; }

    for (int ct = 0; ct < 32; ++ct) {
        bf16x8 Bh0 = cbh[(ct * 2 + 0) * 64 + lane];
        bf16x8 Bh1 = cbh[(ct * 2 + 1) * 64 + lane];
        bf16x8 Bl0 = cbl[(ct * 2 + 0) * 64 + lane];
        bf16x8 Bl1 = cbl[(ct * 2 + 1) * 64 + lane];
        float nev = ne_s[ct * 16 + col];
        int code = ct * 16 + col;
#pragma unroll
        for (int r = 0; r < 2; ++r) {
            f32x4 acc = {0.f, 0.f, 0.f, 0.f};
            acc = __builtin_amdgcn_mfma_f32_16x16x32_bf16(Ah[r][0], Bh0, acc, 0, 0, 0);
            acc = __builtin_amdgcn_mfma_f32_16x16x32_bf16(Ah[r][1], Bh1, acc, 0, 0, 0);
            acc = __builtin_amdgcn_mfma_f32_16x16x32_bf16(Ah[r][0], Bl0, acc, 0, 0, 0);
            acc = __builtin_amdgcn_mfma_f32_16x16x32_bf16(Al[r][0], Bh0, acc, 0, 0, 0);
            acc = __builtin_amdgcn_mfma_f32_16x16x32_bf16(Ah[r][1], Bl1, acc, 0, 0, 0);
            acc = __builtin_amdgcn_mfma_f32_16x16x32_bf16(Al[r][1], Bh1, acc, 0, 0, 0);
            // lo*lo terms ~2^-32 relative: negligible, dropped
#pragma unroll
            for (int e = 0; e < 4; ++e) {
                float sc = fmaf(-2.f, acc[e], nev);   // ||e||^2 - 2 x.e
                bool lt = sc < m1[r][e];
                i1[r][e] = lt ? code : i1[r][e];
                m1[r][e] = lt ? sc : m1[r][e];
            }
        }
    }

    // argmin across the 16 lanes (same q) holding this row's columns
#pragma unroll
    for (int r = 0; r < 2; ++r)
#pragma unroll
        for (int e = 0; e < 4; ++e) {
            float a1 = m1[r][e]; int ai = i1[r][e];
#pragma unroll
            for (int off = 1; off < 16; off <<= 1) {
                float o1 = __shfl_xor(a1, off);
                int   oi = __shfl_xor(ai, off);
                bool tk = (o1 < a1) || (o1 == a1 && oi < ai);  // tie -> lower index
                a1 = tk ? o1 : a1; ai = tk ? oi : ai;
            }
            if (col == 0) sidx[(w * 2 + r) * 16 + q * 4 + e] = ai;
        }
    __syncthreads();

    // --- one-hot rows: 256 f32x2 cols per row, 128 rows (base 8B-aligned) ---
#pragma unroll 4
    for (int i = 0; i < 128; ++i) {
        int id = sidx[i];                      // uniform LDS read -> broadcast
        f32x2 v;
        v.x = ((id >> 1) == tid && (id & 1) == 0) ? 1.f : 0.f;
        v.y = ((id >> 1) == tid && (id & 1) == 1) ? 1.f : 0.f;
        __builtin_nontemporal_store(v, &enc2[(size_t)(n0 + i) * 256 + tid]);
    }

    // --- quantized + loss: lane = row, 32 dims per thread ---
    int tl = tid & 127, dg = tid >> 7;
    int idq = sidx[tl];
    const float4* cq4 = (const float4*)(cb + (size_t)idq * 64 + dg * 32);
    float* qp = out + 1 + (size_t)b * D_ * T_ + (size_t)(dg * 32) * T_ + t0 + tl;

    float lsum = 0.f;
#pragma unroll
    for (int j4 = 0; j4 < 8; ++j4) {
        float4 qv = cq4[j4];
        float qe[4] = {qv.x, qv.y, qv.z, qv.w};
#pragma unroll
        for (int e = 0; e < 4; ++e) {
            int dl = j4 * 4 + e;               // 0..31
            float xv = X[dg * 32 + dl][tl];
            float diff = qe[e] - xv;
            lsum = fmaf(diff, diff, lsum);
            __builtin_nontemporal_store(xv + diff, &qp[(size_t)dl * T_]);
        }
    }
    if (tid < 128) atomicAdd(&hist[idq], 1);   // one count per row (device scope)

#pragma unroll
    for (int off = 32; off > 0; off >>= 1) lsum += __shfl_down(lsum, off);
    __shared__ float wsum[4];
    if ((tid & 63) == 0) wsum[tid >> 6] = lsum;
    __syncthreads();
    if (tid == 0) {
        double s = (double)wsum[0] + (double)wsum[1] + (double)wsum[2] + (double)wsum[3];
        atomicAdd(loss, s);
    }
}

// ---------------- K6: finalize loss + perplexity ----------------------------
__global__ __launch_bounds__(512) void k6_final(const int* __restrict__ hist,
                                                const double* __restrict__ loss,
                                                float* __restrict__ out) {
    __shared__ double sh[512];
    int k = threadIdx.x;
    double p = (double)hist[k] / (double)N_;
    sh[k] = p * log(p + 1e-10);
    __syncthreads();
    for (int s = 256; s > 0; s >>= 1) {
        if (k < s) sh[k] += sh[k + s];
        __syncthreads();
    }
    if (k == 0) {
        out[1 + Q_] = (float)exp(-sh[0]);
        out[0] = (float)(1.25 * (*loss) / (double)Q_);
    }
}

extern "C" void kernel_launch(void* const* d_in, const int* in_sizes, int n_in,
                              void* d_out, int out_size, void* d_ws, size_t ws_size,
                              hipStream_t stream) {
    const float* in = (const float*)d_in[0];   // [16, 64, 4096] fp32
    const float* cb = (const float*)d_in[1];   // [512, 64] fp32
    float* out = (float*)d_out;
    char* ws = (char*)d_ws;

    double* loss  = (double*)(ws + WS_LOSS);
    int* hist     = (int*)(ws + WS_HIST);
    float* ne     = (float*)(ws + WS_NE);
    bf16x8* cbh   = (bf16x8*)(ws + WS_CBH);
    bf16x8* cbl   = (bf16x8*)(ws + WS_CBL);

    f32x2* enc2 = (f32x2*)(out + ENC_OFF);

    k0_init<<<8, 256, 0, stream>>>(cb, ne, hist, loss, cbh, cbl);
    k_main<<<512, 256, 0, stream>>>(in, cb, cbh, cbl, ne, out, enc2, hist, loss);
    k6_final<<<1, 512, 0, stream>>>(hist, loss, out);
}

// Round 9
// 198.045 us; speedup vs baseline: 1.1243x; 1.0503x over previous
//
#include <hip/hip_runtime.h>

#define B_ 16
#define D_ 64
#define T_ 4096
#define K_ 512
#define N_ (B_*T_)        // 65536 vectors
#define Q_ (B_*D_*T_)     // 4194304 quantized elements
#define ENC_OFF ((size_t)(2 + Q_))  // encodings start in d_out

// ws layout (bytes) — ~136 KB
#define WS_LOSS    0        // double
#define WS_HIST    16       // int[512]
#define WS_NE      2064     // float[512]
#define WS_CBH     4608     // bf16x8[32*2*64]  (64 KB) codebook hi frags
#define WS_CBL     70144    // bf16x8[32*2*64]  (64 KB) codebook lo frags

typedef __bf16 bf16x8 __attribute__((ext_vector_type(8)));
typedef float  f32x4  __attribute__((ext_vector_type(4)));

// ---------------- K0: init + ne + codebook hi/lo B-fragments ----------------
// Grid = 8 blocks x 256 threads.
__global__ __launch_bounds__(256) void k0_init(const float* __restrict__ cb,
                                               float* __restrict__ ne,
                                               int* __restrict__ hist,
                                               double* __restrict__ loss,
                                               bf16x8* __restrict__ cbh,
                                               bf16x8* __restrict__ cbl) {
    int bidx = blockIdx.x, tid = threadIdx.x;

    // ne for codes [bidx*64, bidx*64+64)
    if (tid < 64) {
        int code = bidx * 64 + tid;
        float s = 0.f;
#pragma unroll
        for (int d = 0; d < 64; ++d) { float c = cb[code*64 + d]; s = fmaf(c, c, s); }
        ne[code] = s;
    }
    if (bidx == 0) {
        hist[tid] = 0; hist[tid + 256] = 0;
        if (tid == 0) *loss = 0.0;
    }

    // B-frag element (ct,ks,lane,j) = cb[ct*16 + (lane&15)][ks*32 + (lane>>4)*8 + j]
#pragma unroll
    for (int p = 0; p < 2; ++p) {
        int e = p * 256 + tid;          // 0..511
        int ct = bidx * 4 + (e >> 7);
        int ks = (e >> 6) & 1;
        int lane = e & 63;
        int code  = ct * 16 + (lane & 15);
        int dbase = ks * 32 + ((lane >> 4) << 3);
        bf16x8 h, l;
#pragma unroll
        for (int j = 0; j < 8; ++j) {
            float v = cb[code * 64 + dbase + j];
            __bf16 hv = (__bf16)v;
            __bf16 lv = (__bf16)(v - (float)hv);
            h[j] = hv; l[j] = lv;
        }
        cbh[(ct * 2 + ks) * 64 + lane] = h;
        cbl[(ct * 2 + ks) * 64 + lane] = l;
    }
}

// ---------------- K_MAIN: stage + MFMA argmin + one-hot + quant + loss ------
// Block = 256 thr = 4 waves = 64 rows (4 row-tiles, 1 per wave); grid = 1024.
// 64-row blocks: LDS ~19 KB, grid 1024 -> 4 blocks/CU resident (R6 showed the
// 128-row/grid-512 version was occupancy-bound at 2 blocks/CU, 17% occ).
__global__ __launch_bounds__(256) void k_main(const float* __restrict__ in,
                                              const float* __restrict__ cb,
                                              const bf16x8* __restrict__ cbh,
                                              const bf16x8* __restrict__ cbl,
                                              const float* __restrict__ ne,
                                              float* __restrict__ out,
                                              float2* __restrict__ enc2,
                                              int* __restrict__ hist,
                                              double* __restrict__ loss) {
    __shared__ float X[64][65];      // 16.6 KB; all access patterns <=2-way alias (free)
    __shared__ float ne_s[512];
    __shared__ int   sidx[64];
    int tid = threadIdx.x;
    int n0 = blockIdx.x * 64;
    int b  = n0 >> 12, t0 = n0 & (T_ - 1);

    { // stage x-tile: 4096 floats, 16 per thread, coalesced
        int tl = tid & 63, dg = tid >> 6;
#pragma unroll
        for (int i = 0; i < 16; ++i) {
            int d = dg * 16 + i;
            X[d][tl] = in[((size_t)b * 64 + d) * T_ + t0 + tl];
        }
    }
    ne_s[tid] = ne[tid];
    ne_s[tid + 256] = ne[tid + 256];
    __syncthreads();

    int w = tid >> 6, lane = tid & 63;
    int col = lane & 15, q = lane >> 4;

    // A-frags: wave w owns row-tile w. A[m][k=ks*32+q*8+j] = x_row[d]
    bf16x8 Ah[2], Al[2];
#pragma unroll
    for (int ks = 0; ks < 2; ++ks) {
        bf16x8 h, l;
#pragma unroll
        for (int j = 0; j < 8; ++j) {
            float v = X[ks * 32 + q * 8 + j][w * 16 + col];
            __bf16 hv = (__bf16)v;
            __bf16 lv = (__bf16)(v - (float)hv);
            h[j] = hv; l[j] = lv;
        }
        Ah[ks] = h; Al[ks] = l;
    }

    float m1[4]; int i1[4];
#pragma unroll
    for (int e = 0; e < 4; ++e) { m1[e] = 3.4e38f; i1[e] = 0; }

    for (int ct = 0; ct < 32; ++ct) {
        bf16x8 Bh0 = cbh[(ct * 2 + 0) * 64 + lane];
        bf16x8 Bh1 = cbh[(ct * 2 + 1) * 64 + lane];
        bf16x8 Bl0 = cbl[(ct * 2 + 0) * 64 + lane];
        bf16x8 Bl1 = cbl[(ct * 2 + 1) * 64 + lane];
        float nev = ne_s[ct * 16 + col];
        int code = ct * 16 + col;
        f32x4 acc = {0.f, 0.f, 0.f, 0.f};
        acc = __builtin_amdgcn_mfma_f32_16x16x32_bf16(Ah[0], Bh0, acc, 0, 0, 0);
        acc = __builtin_amdgcn_mfma_f32_16x16x32_bf16(Ah[1], Bh1, acc, 0, 0, 0);
        acc = __builtin_amdgcn_mfma_f32_16x16x32_bf16(Ah[0], Bl0, acc, 0, 0, 0);
        acc = __builtin_amdgcn_mfma_f32_16x16x32_bf16(Al[0], Bh0, acc, 0, 0, 0);
        acc = __builtin_amdgcn_mfma_f32_16x16x32_bf16(Ah[1], Bl1, acc, 0, 0, 0);
        acc = __builtin_amdgcn_mfma_f32_16x16x32_bf16(Al[1], Bh1, acc, 0, 0, 0);
        // lo*lo terms ~2^-32 relative: negligible, dropped
#pragma unroll
        for (int e = 0; e < 4; ++e) {
            float sc = fmaf(-2.f, acc[e], nev);   // ||e||^2 - 2 x.e
            bool lt = sc < m1[e];
            i1[e] = lt ? code : i1[e];
            m1[e] = lt ? sc : m1[e];
        }
    }

    // argmin across the 16 lanes (same q) holding this row's columns
#pragma unroll
    for (int e = 0; e < 4; ++e) {
        float a1 = m1[e]; int ai = i1[e];
#pragma unroll
        for (int off = 1; off < 16; off <<= 1) {
            float o1 = __shfl_xor(a1, off);
            int   oi = __shfl_xor(ai, off);
            bool tk = (o1 < a1) || (o1 == a1 && oi < ai);  // tie -> lower index
            a1 = tk ? o1 : a1; ai = tk ? oi : ai;
        }
        if (col == 0) sidx[w * 16 + q * 4 + e] = ai;
    }
    __syncthreads();

    // --- one-hot rows: 256 float2 cols per row, 64 rows (base 8B-aligned) ---
#pragma unroll 4
    for (int i = 0; i < 64; ++i) {
        int id = sidx[i];                      // uniform LDS read -> broadcast
        float2 v;
        v.x = ((id >> 1) == tid && (id & 1) == 0) ? 1.f : 0.f;
        v.y = ((id >> 1) == tid && (id & 1) == 1) ? 1.f : 0.f;
        enc2[(size_t)(n0 + i) * 256 + tid] = v;
    }

    // --- quantized + loss: lane = row, 16 dims per thread ---
    int tl = tid & 63, dg = tid >> 6;
    int idq = sidx[tl];
    const float4* cq4 = (const float4*)(cb + (size_t)idq * 64 + dg * 16);
    float* qp = out + 1 + (size_t)b * D_ * T_ + (size_t)(dg * 16) * T_ + t0 + tl;

    float lsum = 0.f;
#pragma unroll
    for (int j4 = 0; j4 < 4; ++j4) {
        float4 qv = cq4[j4];
        float qe[4] = {qv.x, qv.y, qv.z, qv.w};
#pragma unroll
        for (int e = 0; e < 4; ++e) {
            int dl = j4 * 4 + e;               // 0..15
            float xv = X[dg * 16 + dl][tl];
            float diff = qe[e] - xv;
            lsum = fmaf(diff, diff, lsum);
            qp[(size_t)dl * T_] = xv + diff;   // straight-through: x + (q - x)
        }
    }
    if (tid < 64) atomicAdd(&hist[idq], 1);    // one count per row (device scope)

#pragma unroll
    for (int off = 32; off > 0; off >>= 1) lsum += __shfl_down(lsum, off);
    __shared__ float wsum[4];
    if ((tid & 63) == 0) wsum[tid >> 6] = lsum;
    __syncthreads();
    if (tid == 0) {
        double s = (double)wsum[0] + (double)wsum[1] + (double)wsum[2] + (double)wsum[3];
        atomicAdd(loss, s);
    }
}

// ---------------- K6: finalize loss + perplexity ----------------------------
__global__ __launch_bounds__(512) void k6_final(const int* __restrict__ hist,
                                                const double* __restrict__ loss,
                                                float* __restrict__ out) {
    __shared__ double sh[512];
    int k = threadIdx.x;
    double p = (double)hist[k] / (double)N_;
    sh[k] = p * log(p + 1e-10);
    __syncthreads();
    for (int s = 256; s > 0; s >>= 1) {
        if (k < s) sh[k] += sh[k + s];
        __syncthreads();
    }
    if (k == 0) {
        out[1 + Q_] = (float)exp(-sh[0]);
        out[0] = (float)(1.25 * (*loss) / (double)Q_);
    }
}

extern "C" void kernel_launch(void* const* d_in, const int* in_sizes, int n_in,
                              void* d_out, int out_size, void* d_ws, size_t ws_size,
                              hipStream_t stream) {
    const float* in = (const float*)d_in[0];   // [16, 64, 4096] fp32
    const float* cb = (const float*)d_in[1];   // [512, 64] fp32
    float* out = (float*)d_out;
    char* ws = (char*)d_ws;

    double* loss  = (double*)(ws + WS_LOSS);
    int* hist     = (int*)(ws + WS_HIST);
    float* ne     = (float*)(ws + WS_NE);
    bf16x8* cbh   = (bf16x8*)(ws + WS_CBH);
    bf16x8* cbl   = (bf16x8*)(ws + WS_CBL);

    float2* enc2 = (float2*)(out + ENC_OFF);

    k0_init<<<8, 256, 0, stream>>>(cb, ne, hist, loss, cbh, cbl);
    k_main<<<N_ / 64, 256, 0, stream>>>(in, cb, cbh, cbl, ne, out, enc2, hist, loss);
    k6_final<<<1, 512, 0, stream>>>(hist, loss, out);
}